// Round 16
// baseline (4504.849 us; speedup 1.0000x reference)
//
#include <hip/hip_runtime.h>

// DeepLSTM persistent wavefront pipeline for MI355X (gfx950).
// R16: XCD-local recurrence with a SINGLE placement-oblivious protocol.
// 8 groups (layer,half) x 32 WGs; g = blockIdx&7 (round-robin bid->XCD
// heuristic; correctness never depends on it). h ring is DOUBLE-STORED
// (sc0 -> producer-XCD L2 dirty line, sc0sc1 -> MALL). Same-XCD readers'
// cached loads hit the shared L2; cross-XCD readers miss to the fresh MALL
// copy. Recurrent flags: frec_fast (sc0, after local h ack, vmcnt(1)) and
// frec_safe (sc1, after full MALL drain); consumers poll fast via sc0 with
// every-4th sc1 fallback. Inter-layer edge via MALL write-once byte flags.
// No handshake, no modes, all polls spin-capped (fail-loud, never hang).

constexpr int Bv = 32;
constexpr int Tv = 512;
constexpr int Iv = 256;
constexpr int Hv = 512;
constexpr int LAYv = 4;
constexpr int THREADS = 256; // 4 waves; wave w = N-tile
constexpr int NKK = 32;      // K/32 (512 rec + 512 in)
constexpr int WTABH = 4 * NKK * 64 * 8; // shorts, hi table = 128KB
constexpr int SCR_STRIDE = 20;
constexpr unsigned SMEM_BYTES = WTABH * 2 + 4 * 16 * SCR_STRIDE * 4; // 136192
constexpr int SPIN_CAP = 1 << 16; // fail-loud, never hang

typedef short sfrag __attribute__((ext_vector_type(8)));
typedef float facc __attribute__((ext_vector_type(4)));
typedef float f32x4 __attribute__((ext_vector_type(4)));

struct Params {
  const float *x;
  const float *Wx0i, *Wx0f, *Wx0o, *Wx0c;
  const float *Wxi, *Wxf, *Wxo, *Wxc;
  const float *Whi, *Whf, *Who, *Whc;
  const float *bi, *bf, *bo, *bc;
  float *out;
  unsigned short *hmall; // [dmask+1][8 g][16][512] bf16 ring, double-stored
  unsigned char *fsm;    // [512][8 g][32 rank][4 w] bytes, write-once (MALL)
  unsigned short *ffast; // [2][8 g][128] ushort, value-coded (L2-local)
  unsigned short *fsafe; // [2][8 g][128] ushort, value-coded (MALL)
  int dmask;
};

__device__ __forceinline__ unsigned short f2bf(float f) {
  unsigned int u = __builtin_bit_cast(unsigned int, f);
  u += 0x7FFFu + ((u >> 16) & 1u); // RNE
  return (unsigned short)(u >> 16);
}
__device__ __forceinline__ float bf2f(unsigned short s) {
  unsigned int u = ((unsigned int)s) << 16;
  return __builtin_bit_cast(float, u);
}

// ---- cache-control primitives ----
__device__ __forceinline__ unsigned ld_u32_sc0(const int *p) { // L1-bypass, L2 hit
  unsigned v;
  asm volatile("global_load_dword %0, %1, off sc0\n\ts_waitcnt vmcnt(0)"
               : "=v"(v) : "v"(p) : "memory");
  return v;
}
__device__ __forceinline__ unsigned ld_u32_byp(const int *p) { // full bypass (MALL)
  unsigned v;
  asm volatile("global_load_dword %0, %1, off sc0 sc1\n\ts_waitcnt vmcnt(0)"
               : "=v"(v) : "v"(p) : "memory");
  return v;
}
// double store: local-L2 dirty copy + MALL copy (same value, order-free)
__device__ __forceinline__ void st2_short(unsigned short *p, unsigned short v) {
  asm volatile("global_store_short %0, %1, off sc0\n\t"
               "global_store_short %0, %1, off sc0 sc1" ::"v"(p), "v"(v)
               : "memory");
}
__device__ __forceinline__ void st_short_sc0(unsigned short *p, unsigned short v) {
  asm volatile("global_store_short %0, %1, off sc0" ::"v"(p), "v"(v) : "memory");
}
__device__ __forceinline__ void st_short_byp(unsigned short *p, unsigned short v) {
  asm volatile("global_store_short %0, %1, off sc0 sc1" ::"v"(p), "v"(v) : "memory");
}
__device__ __forceinline__ void st_u8_byp(unsigned char *p) {
  asm volatile("global_store_byte %0, %1, off sc0 sc1" ::"v"(p), "v"(1) : "memory");
}

__global__ void __launch_bounds__(THREADS, 1) lstm_pipeline(Params p) {
  const int bid = blockIdx.x;
  const int g = bid & 7;        // XCD-candidate group (layer,half)
  const int rank = bid >> 3;    // 0..31: 16-unit slice
  const int l = g >> 1, mt = g & 1;
  const int gsrc = g - 2;       // producer group of the inter-layer edge
  const int tid = threadIdx.x;
  const int lane = tid & 63;
  const int w = tid >> 6;       // wave = N-tile (4 x 16 gate-cols)
  const int kgrp = lane >> 4;

  extern __shared__ char smem[];
  unsigned short *wlds_hi = (unsigned short *)smem;          // [4][32][64][8]
  float *scratch = (float *)(smem + (size_t)WTABH * 2) +
                   (size_t)w * 16 * SCR_STRIDE;              // wave-private

  // gate-indexed weight bases for this layer
  const float *Wh[4] = {p.Whi + (size_t)l * Hv * Hv, p.Whf + (size_t)l * Hv * Hv,
                        p.Who + (size_t)l * Hv * Hv, p.Whc + (size_t)l * Hv * Hv};
  const float *Wx[4];
  if (l == 0) { Wx[0] = p.Wx0i; Wx[1] = p.Wx0f; Wx[2] = p.Wx0o; Wx[3] = p.Wx0c; }
  else {
    size_t o = (size_t)(l - 1) * Hv * Hv;
    Wx[0] = p.Wxi + o; Wx[1] = p.Wxf + o; Wx[2] = p.Wxo + o; Wx[3] = p.Wxc + o;
  }
  const int kx_max = (l == 0) ? Iv : Hv;

  // ---- stage HI weights into LDS (this WG's 16 units -> 64 gate-cols) ----
  for (int idx = tid; idx < 4 * NKK * 64; idx += THREADS) {
    int lanei = idx & 63;
    int kk = (idx >> 6) & (NKK - 1);
    int nti = idx >> 11; // 0..3
    int kbase = kk * 32 + (lanei >> 4) * 8;
    int n = nti * 16 + (lanei & 15);
    int u = n >> 2, gg = n & 3;
    int col = rank * 16 + u;
    sfrag vh;
#pragma unroll
    for (int j = 0; j < 8; ++j) {
      int k = kbase + j;
      float wv;
      if (k < Hv) wv = Wh[gg][(size_t)k * Hv + col];
      else { int kx = k - Hv; wv = (kx < kx_max) ? Wx[gg][(size_t)kx * Hv + col] : 0.f; }
      vh[j] = (short)f2bf(wv);
    }
    *(sfrag *)&wlds_hi[(size_t)idx * 8] = vh;
  }
  // ---- stage LO weights into VGPRs (this wave's 32 fragments) ----
  sfrag lov[NKK];
#pragma unroll
  for (int kk = 0; kk < NKK; ++kk) {
    int kbase = kk * 32 + kgrp * 8;
    int n = w * 16 + (lane & 15);
    int u = n >> 2, gg = n & 3;
    int col = rank * 16 + u;
    sfrag vl;
#pragma unroll
    for (int j = 0; j < 8; ++j) {
      int k = kbase + j;
      float wv;
      if (k < Hv) wv = Wh[gg][(size_t)k * Hv + col];
      else { int kx = k - Hv; wv = (kx < kx_max) ? Wx[gg][(size_t)kx * Hv + col] : 0.f; }
      unsigned short h16 = f2bf(wv);
      vl[j] = (short)f2bf(wv - bf2f(h16));
    }
    lov[kk] = vl;
  }

  // epilogue mapping: one (row,unit) per lane; wave tile = 16 rows x 4 units
  const int er = lane >> 2, eu = lane & 3;
  const int ju = rank * 16 + w * 4 + eu;
  const float bia_i = p.bi[l * Hv + ju];
  const float bia_f = p.bf[l * Hv + ju];
  const float bia_o = p.bo[l * Hv + ju];
  const float bia_c = p.bc[l * Hv + ju];
  float cst = 0.f;

  __syncthreads(); // weights staged -- only barrier in the kernel

  unsigned short *hmall = p.hmall, *ffast = p.ffast, *fsafe = p.fsafe;
  unsigned char *fsm = p.fsm;
  const int dmask = p.dmask;

#define GEMM16(A, KKB)                                                         \
  {                                                                            \
    _Pragma("unroll") for (int j = 0; j < 16; ++j) {                           \
      sfrag bh = *(const sfrag *)&wlds_hi[(size_t)(((w * NKK) + (KKB) + j) * 64 + lane) * 8]; \
      acc0 = __builtin_amdgcn_mfma_f32_16x16x32_bf16(A[j], bh, acc0, 0, 0, 0); \
      acc1 = __builtin_amdgcn_mfma_f32_16x16x32_bf16(A[j], lov[(KKB) + j], acc1, 0, 0, 0); \
    }                                                                          \
  }

  for (int t = 0; t < Tv; ++t) {
    facc acc0 = {0.f, 0.f, 0.f, 0.f};
    facc acc1 = {0.f, 0.f, 0.f, 0.f};

    // ================= input half =================
    if (l == 0) {
      const float *xbp =
          p.x + ((size_t)(mt * 16 + (lane & 15)) * Tv + t) * Iv + kgrp * 8;
#pragma unroll
      for (int kk = 0; kk < 8; ++kk) {
        f32x4 lo = *(const f32x4 *)(xbp + kk * 32);
        f32x4 hi = *(const f32x4 *)(xbp + kk * 32 + 4);
        sfrag ax;
#pragma unroll
        for (int j = 0; j < 4; ++j) { ax[j] = (short)f2bf(lo[j]); ax[4 + j] = (short)f2bf(hi[j]); }
        sfrag bh = *(const sfrag *)&wlds_hi[(size_t)(((w * NKK) + 16 + kk) * 64 + lane) * 8];
        acc0 = __builtin_amdgcn_mfma_f32_16x16x32_bf16(ax, bh, acc0, 0, 0, 0);
        acc1 = __builtin_amdgcn_mfma_f32_16x16x32_bf16(ax, lov[16 + kk], acc1, 0, 0, 0);
      }
    } else {
      // inter-layer flag (always MALL), then cached panel read
      {
        const int *fb = (const int *)(fsm + ((size_t)t * 8 + gsrc) * 128);
        int spin = 0;
        for (;;) {
          int v = (lane < 32) ? (int)ld_u32_byp(fb + lane) : 0x01010101;
          if (__all(v == 0x01010101) || ++spin > SPIN_CAP) break;
          __builtin_amdgcn_s_sleep(1);
        }
      }
      const unsigned short *hin =
          hmall + (((size_t)((t + 1) & dmask) * 8 + gsrc) * 16 + (lane & 15)) * 512;
      sfrag ain[16];
#pragma unroll
      for (int kk = 0; kk < 16; ++kk)
        ain[kk] = *(const sfrag *)(hin + kk * 32 + kgrp * 8);
      GEMM16(ain, 16)
    }

    // ================= recurrent half =================
    if (t > 0) {
      // poll frec: sc0 fast path (same-XCD L2), every-4th sc1 safe fallback
      {
        const int *pf = (const int *)(ffast + (size_t)((t & 1) * 8 + g) * 128) + lane;
        const int *ps = (const int *)(fsafe + (size_t)((t & 1) * 8 + g) * 128) + lane;
        const unsigned exp32 = (unsigned)t * 0x10001u;
        int spin = 0;
        for (;;) {
          unsigned v = ((spin & 3) == 3) ? ld_u32_byp(ps) : ld_u32_sc0(pf);
          if (__all(v == exp32) || ++spin > SPIN_CAP) break;
          __builtin_amdgcn_s_sleep(1);
        }
      }
      const unsigned short *hrec =
          hmall + (((size_t)(t & dmask) * 8 + g) * 16 + (lane & 15)) * 512;
      sfrag arec[16];
#pragma unroll
      for (int kk = 0; kk < 16; ++kk)
        arec[kk] = *(const sfrag *)(hrec + kk * 32 + kgrp * 8);
      GEMM16(arec, 0)
    } // t==0: h=0 contributes nothing

    // ---- in-wave transpose via wave-private scratch (no barrier) ----
    {
      int rl = (lane >> 4) * 4, cl = lane & 15;
#pragma unroll
      for (int r = 0; r < 4; ++r)
        scratch[(rl + r) * SCR_STRIDE + cl] = acc0[r] + acc1[r];
    }
    f32x4 q = *(const f32x4 *)&scratch[er * SCR_STRIDE + eu * 4];

    // ---- gates / state: one chain per lane ----
    float pi = q[0] + bia_i, pf_ = q[1] + bia_f, po = q[2] + bia_o, pc = q[3] + bia_c;
    float gi = 1.f / (1.f + __expf(-pi));
    float gf = 1.f / (1.f + __expf(-pf_));
    float go = 1.f / (1.f + __expf(-po));
    float gc = tanhf(pc);
    cst = gf * cst + gi * gc;
    float hval = go * tanhf(cst);
    unsigned short hbf = f2bf(hval);

    // ---- tail: double-store h, staged flags ----
    st2_short(&hmall[(((size_t)((t + 1) & dmask) * 8 + g) * 16 + er) * 512 + ju], hbf);
    asm volatile("s_waitcnt vmcnt(1)" ::: "memory"); // local (sc0) h ack'd in L2
    if (lane == 0)
      st_short_sc0(ffast + (size_t)(((t + 1) & 1) * 8 + g) * 128 + rank * 4 + w,
                   (unsigned short)(t + 1));
    asm volatile("s_waitcnt vmcnt(0)" ::: "memory"); // MALL h copy ack'd
    if (lane == 0) {
      st_short_byp(fsafe + (size_t)(((t + 1) & 1) * 8 + g) * 128 + rank * 4 + w,
                   (unsigned short)(t + 1));
      if (l < LAYv - 1)
        st_u8_byp(fsm + ((size_t)t * 8 + g) * 128 + rank * 4 + w);
    }
    if (l == LAYv - 1) // final output, no ordering requirement
      p.out[((size_t)(mt * 16 + er) * Tv + t) * Hv + ju] = hval;
  }
#undef GEMM16
}

extern "C" void kernel_launch(void *const *d_in, const int *in_sizes, int n_in,
                              void *d_out, int out_size, void *d_ws, size_t ws_size,
                              hipStream_t stream) {
  Params prm;
  prm.x = (const float *)d_in[0];
  prm.Wx0i = (const float *)d_in[1];
  prm.Wx0f = (const float *)d_in[2];
  prm.Wx0o = (const float *)d_in[3];
  prm.Wx0c = (const float *)d_in[4];
  prm.Wxi = (const float *)d_in[5];
  prm.Wxf = (const float *)d_in[6];
  prm.Wxo = (const float *)d_in[7];
  prm.Wxc = (const float *)d_in[8];
  prm.Whi = (const float *)d_in[9];
  prm.Whf = (const float *)d_in[10];
  prm.Who = (const float *)d_in[11];
  prm.Whc = (const float *)d_in[12];
  prm.bi = (const float *)d_in[13];
  prm.bf = (const float *)d_in[14];
  prm.bo = (const float *)d_in[15];
  prm.bc = (const float *)d_in[16];
  prm.out = (float *)d_out;

  size_t slot_b = (size_t)8 * 16 * 512 * 2; // 128KB per t-slot (all 8 groups)
  size_t fsm_b = (size_t)512 * 8 * 128;     // 512KB
  size_t ff_b = (size_t)2 * 8 * 128 * 2;    // 4KB
  size_t hslots = 512;                      // read-once ring
  if (ws_size < hslots * slot_b + fsm_b + 2 * ff_b) {
    hslots = 256; // fallback: slot reuse 256 steps apart
    if (ws_size < hslots * slot_b + fsm_b + 2 * ff_b) return;
  }
  prm.dmask = (int)hslots - 1;
  char *base = (char *)d_ws;
  prm.hmall = (unsigned short *)base;
  prm.fsm = (unsigned char *)(base + hslots * slot_b);
  prm.ffast = (unsigned short *)(base + hslots * slot_b + fsm_b);
  prm.fsafe = (unsigned short *)(base + hslots * slot_b + fsm_b + ff_b);

  // zero all flags (contiguous) every call -- deterministic replays
  hipMemsetAsync(prm.fsm, 0, fsm_b + 2 * ff_b, stream);

  hipFuncSetAttribute(reinterpret_cast<const void *>(lstm_pipeline),
                      hipFuncAttributeMaxDynamicSharedMemorySize, (int)SMEM_BYTES);

  // 136KB LDS -> 1 WG/CU; grid 256 == #CUs -> co-resident.
  hipLaunchKernelGGL(lstm_pipeline, dim3(256), dim3(THREADS), SMEM_BYTES,
                     stream, prm);
}